// Round 11
// baseline (968.690 us; speedup 1.0000x reference)
//
#include <hip/hip_runtime.h>
#include <cstddef>
#include <cstdint>

// AdaConvBlock on MI355X — round 11.
// GEMM family = round-7 config (core3, K-chunk 128, RSA=136 — best measured).
// Conv = k_convW32: 32 consecutive outputs/thread, 128-thread blocks
// (2 waves per (b,c) row): rolling windows give 9.6 LDS-reads/output
// (vs 17.7 at r7) while keeping 14 waves/CU (vs 8 at W=64).
// Index algebra is the r9-debugged W=64 code with the 16->8 substitution.

namespace {

constexpr int B_  = 16;
constexpr int C_  = 384;
constexpr int L_  = 4096;
constexpr int KADA = 128;
constexpr int KS  = 32;
constexpr int NB  = 6 * 33;
constexpr float EPS_ = 1e-5f;
constexpr int RSA = 136;        // LDS row stride (bf16) for staged GEMM tiles

typedef unsigned short u16;
typedef __attribute__((ext_vector_type(8))) short bf16x8;
typedef __attribute__((ext_vector_type(4))) float f32x4;
typedef __attribute__((ext_vector_type(4))) float f4;

__device__ __forceinline__ float4 ld4(const float* p) { return *reinterpret_cast<const float4*>(p); }
__device__ __forceinline__ void st4(float* p, float4 v) { *reinterpret_cast<float4*>(p) = v; }
__device__ __forceinline__ float siluf(float z) { return z / (1.f + expf(-z)); }
__device__ __forceinline__ float geluf(float z) { return 0.5f * z * (1.f + erff(z * 0.70710678118654752f)); }
__device__ __forceinline__ u16 f2b(float x) {
  union { float f; uint32_t u; } a; a.f = x;
  const uint32_t u = a.u;
  return (u16)((u + 0x7fffu + ((u >> 16) & 1u)) >> 16);
}
__device__ __forceinline__ float b2f(u16 h) {
  union { uint32_t u; float f; } a; a.u = ((uint32_t)h) << 16; return a.f;
}
__device__ __forceinline__ bf16x8 ldb8(const u16* p) { return *reinterpret_cast<const bf16x8*>(p); }
__device__ __forceinline__ void stb8(u16* p, bf16x8 v) { *reinterpret_cast<bf16x8*>(p) = v; }

// ---------------- boundary-weight precompute (per channel) ----------------
__global__ __launch_bounds__(64) void k_kw(const float* __restrict__ kern, float* __restrict__ wb) {
  const int c = blockIdx.x;
  const int t = threadIdx.x;
  constexpr float SC[6] = {32.f, 16.f, 8.f, 4.f, 2.f, 1.f};
  constexpr int REP[6] = {1, 1, 2, 4, 8, 16};
  float part = 0.f;
  for (int idx = t; idx < 192; idx += 64) {
    const int i = idx >> 5, r = idx & 31;
    const float v = kern[(i * C_ + c) * KS + r] * SC[i];
    part += v * v * (float)REP[i];
  }
  for (int m = 1; m < 64; m <<= 1) part += __shfl_xor(part, m);
  const float rinv = 1.f / sqrtf(part);
  for (int jj = t; jj < NB; jj += 64) {
    const int i = jj / 33, r = jj - 33 * i;
    const float sc = SC[i] * rinv;
    float bwv;
    if (r == 0) bwv = kern[(i * C_ + c) * KS + 0] * sc;
    else if (r == 32) bwv = -kern[(i * C_ + c) * KS + 31] * sc;
    else bwv = (kern[(i * C_ + c) * KS + r] - kern[(i * C_ + c) * KS + r - 1]) * sc;
    wb[c * NB + jj] = bwv;
  }
}

// ---------------- weight f32 -> bf16 convert ----------------
__global__ __launch_bounds__(256) void k_wcvt(const float* __restrict__ src, u16* __restrict__ dst) {
  const size_t i = ((size_t)blockIdx.x * 256 + threadIdx.x) * 8;
  const float4 a = ld4(src + i);
  const float4 b = ld4(src + i + 4);
  bf16x8 v;
  v[0] = (short)f2b(a.x); v[1] = (short)f2b(a.y); v[2] = (short)f2b(a.z); v[3] = (short)f2b(a.w);
  v[4] = (short)f2b(b.x); v[5] = (short)f2b(b.y); v[6] = (short)f2b(b.z); v[7] = (short)f2b(b.w);
  stb8(dst + i, v);
}

// ---------------- STT[b][l][128] = bf16(silu(t_cond[b][k][l])) ----------------
__global__ __launch_bounds__(256) void k_tsilu(const float* __restrict__ in, u16* __restrict__ out) {
  __shared__ float T[64][65];
  const int t = threadIdx.x;
  const int lb = blockIdx.x * 64;
  const int kb = blockIdx.y * 64;
  const int b  = blockIdx.z;
  const float* src = in + ((size_t)b * KADA + kb) * L_ + lb;
  const int ll = t & 63;
  const int kq = t >> 6;
  #pragma unroll
  for (int j = 0; j < 16; ++j) {
    const int k = kq * 16 + j;
    T[k][ll] = siluf(src[(size_t)k * L_ + ll]);
  }
  __syncthreads();
  const int g = t & 7;
  #pragma unroll
  for (int j = 0; j < 2; ++j) {
    const int l = (t >> 3) + 32 * j;
    bf16x8 v;
    #pragma unroll
    for (int i = 0; i < 8; ++i) v[i] = (short)f2b(T[8 * g + i][l]);
    stb8(out + ((size_t)b * L_ + lb + l) * KADA + kb + 8 * g, v);
  }
}

// ---------------- per-(b,l) mean / rsigma over C, 4 l per thread ----------------
__global__ __launch_bounds__(256) void k_mv4(const float* __restrict__ x,
                                             float* __restrict__ mu, float* __restrict__ rs) {
  const int g4 = blockIdx.x * 256 + threadIdx.x;   // [0, B*L/4)
  const int b = g4 >> 10;
  const int l = (g4 & 1023) * 4;
  const float* p = x + (size_t)b * C_ * L_ + l;
  f4 s = {0.f, 0.f, 0.f, 0.f}, ss = {0.f, 0.f, 0.f, 0.f};
  #pragma unroll 4
  for (int c = 0; c < C_; ++c) {
    const f4 v = *reinterpret_cast<const f4*>(p + (size_t)c * L_);
    s += v; ss += v * v;
  }
  f4 m4, r4;
  #pragma unroll
  for (int e = 0; e < 4; ++e) {
    const float m = s[e] * (1.f / (float)C_);
    const float var = ss[e] * (1.f / (float)C_) - m * m;
    m4[e] = m;
    r4[e] = 1.f / sqrtf(var + EPS_);
  }
  *reinterpret_cast<f4*>(mu + (size_t)b * L_ + l) = m4;
  *reinterpret_cast<f4*>(rs + (size_t)b * L_ + l) = r4;
}

// ---------------- MFMA GEMM core v3 (r7 config: K chunked at 128) ----------------
template <int KD, int NBOP>
__device__ __forceinline__ void gemm_core3(const u16* __restrict__ Ab,
                                           const u16* __restrict__ B0b,
                                           const u16* __restrict__ B1b,
                                           u16* As, u16* Bs,
                                           f32x4 (&acc0)[4][4], f32x4 (&acc1)[4][4]) {
  constexpr int WC = (NBOP == 2) ? 2 : 4;
  const int tid = threadIdx.x;
  const int lane = tid & 63;
  const int wid = tid >> 6;
  const int wl = (wid & 1) * 64;
  const int wc = (wid >> 1) * ((NBOP == 2) ? 32 : 64);
  const int frow = lane & 15;
  const int fk8 = (lane >> 4) * 8;
  const int rr = tid >> 4;            // staging row 0..15
  const int c8 = (tid & 15) * 8;      // staging col

  for (int kc = 0; kc < KD; kc += 128) {
    __syncthreads();
    #pragma unroll
    for (int j = 0; j < 8; ++j)
      stb8(As + (j * 16 + rr) * RSA + c8, ldb8(Ab + (size_t)(j * 16 + rr) * KD + kc + c8));
    #pragma unroll
    for (int j = 0; j < 4; ++j)
      stb8(Bs + (j * 16 + rr) * RSA + c8, ldb8(B0b + (size_t)(j * 16 + rr) * KD + kc + c8));
    #pragma unroll
    for (int j = 0; j < 4; ++j)
      stb8(Bs + ((j + 4) * 16 + rr) * RSA + c8, ldb8(B1b + (size_t)(j * 16 + rr) * KD + kc + c8));
    __syncthreads();
    #pragma unroll
    for (int ks = 0; ks < 128; ks += 32) {
      bf16x8 af[4], b0f[WC], b1f[WC];
      #pragma unroll
      for (int fi = 0; fi < 4; ++fi)
        af[fi] = ldb8(As + (wl + fi * 16 + frow) * RSA + ks + fk8);
      #pragma unroll
      for (int fj = 0; fj < WC; ++fj) {
        b0f[fj] = ldb8(Bs + (wc + fj * 16 + frow) * RSA + ks + fk8);
        if constexpr (NBOP == 2)
          b1f[fj] = ldb8(Bs + (64 + wc + fj * 16 + frow) * RSA + ks + fk8);
      }
      #pragma unroll
      for (int fi = 0; fi < 4; ++fi)
        #pragma unroll
        for (int fj = 0; fj < WC; ++fj) {
          acc0[fi][fj] = __builtin_amdgcn_mfma_f32_16x16x32_bf16(af[fi], b0f[fj], acc0[fi][fj], 0, 0, 0);
          if constexpr (NBOP == 2)
            acc1[fi][fj] = __builtin_amdgcn_mfma_f32_16x16x32_bf16(af[fi], b1f[fj], acc1[fi][fj], 0, 0, 0);
        }
    }
  }
}

// ---------------- ada GEMMs ----------------
// MODE 0: LN1-mod -> y_mod f32 [c][l]   (block 128l x 64c, dual shift/scale)
// MODE 1: LN2-mod -> Y3T bf16 [l][c]    (block 128l x 64c, dual shift/scale)
// MODE 2: gate_tm -> G bf16 [c][l]      (block 128l x 128c)
template <int MODE>
__global__ __launch_bounds__(256) void k_adagemm(const u16* __restrict__ AWB,
                                                 const float* __restrict__ ada_b,
                                                 const u16* __restrict__ STT,
                                                 const float* __restrict__ src,
                                                 const float* __restrict__ mu,
                                                 const float* __restrict__ rs,
                                                 float* __restrict__ dstf,
                                                 u16* __restrict__ dstb,
                                                 int base0, int base1) {
  __shared__ u16 As[128 * RSA];
  __shared__ u16 Bs[128 * RSA];
  const int lb = blockIdx.x * 128;
  const int b  = blockIdx.z;
  f32x4 acc0[4][4] = {};
  f32x4 acc1[4][4] = {};
  constexpr int NBOP = (MODE == 2) ? 1 : 2;
  const int cb = blockIdx.y * ((MODE == 2) ? 128 : 64);
  const u16* B0b;
  const u16* B1b;
  if constexpr (MODE == 2) {
    B0b = AWB + (size_t)(base0 + cb) * KADA;
    B1b = AWB + (size_t)(base0 + cb + 64) * KADA;
  } else {
    B0b = AWB + (size_t)(base0 + cb) * KADA;
    B1b = AWB + (size_t)(base1 + cb) * KADA;
  }
  gemm_core3<KADA, NBOP>(STT + ((size_t)b * L_ + lb) * KADA, B0b, B1b, As, Bs, acc0, acc1);

  const int lane = threadIdx.x & 63;
  const int wid = threadIdx.x >> 6;
  const int wl = (wid & 1) * 64;
  const int wc = (wid >> 1) * ((NBOP == 2) ? 32 : 64);
  const int frow = lane & 15;
  const int fq = (lane >> 4) * 4;
  constexpr int WC = (NBOP == 2) ? 2 : 4;
  #pragma unroll
  for (int fi = 0; fi < 4; ++fi) {
    const int lg = lb + wl + fi * 16 + fq;
    float4 m4, r4;
    if (MODE != 2) { m4 = ld4(mu + (size_t)b * L_ + lg); r4 = ld4(rs + (size_t)b * L_ + lg); }
    #pragma unroll
    for (int fj = 0; fj < WC; ++fj) {
      const int cg = cb + wc + fj * 16 + frow;
      const size_t n = ((size_t)b * C_ + cg) * L_ + lg;
      if (MODE == 2) {
        const float bg = ada_b[base0 + cg];
        const u16 h0 = f2b(acc0[fi][fj][0] + bg);
        const u16 h1 = f2b(acc0[fi][fj][1] + bg);
        const u16 h2 = f2b(acc0[fi][fj][2] + bg);
        const u16 h3 = f2b(acc0[fi][fj][3] + bg);
        uint2 pk;
        pk.x = (uint32_t)h0 | ((uint32_t)h1 << 16);
        pk.y = (uint32_t)h2 | ((uint32_t)h3 << 16);
        *reinterpret_cast<uint2*>(dstb + n) = pk;
      } else {
        const float bsh = ada_b[base0 + cg];
        const float bsc = ada_b[base1 + cg];
        const float4 xv = ld4(src + n);
        float o[4];
        o[0] = (xv.x - m4.x) * r4.x * (1.f + acc1[fi][fj][0] + bsc) + acc0[fi][fj][0] + bsh;
        o[1] = (xv.y - m4.y) * r4.y * (1.f + acc1[fi][fj][1] + bsc) + acc0[fi][fj][1] + bsh;
        o[2] = (xv.z - m4.z) * r4.z * (1.f + acc1[fi][fj][2] + bsc) + acc0[fi][fj][2] + bsh;
        o[3] = (xv.w - m4.w) * r4.w * (1.f + acc1[fi][fj][3] + bsc) + acc0[fi][fj][3] + bsh;
        if (MODE == 0) {
          st4(dstf + n, float4{o[0], o[1], o[2], o[3]});
        } else {
          u16* d = dstb + ((size_t)b * L_ + lg) * C_ + cg;
          #pragma unroll
          for (int i = 0; i < 4; ++i) d[(size_t)i * C_] = f2b(o[i]);
        }
      }
    }
  }
}

// ---------------- MLP GEMM1: HT[l][h] = bf16(gelu(w1 @ y3 + b1)) ----------------
__global__ __launch_bounds__(256) void k_mlp1(const u16* __restrict__ Y3T,
                                              const u16* __restrict__ W1B,
                                              const float* __restrict__ b1,
                                              u16* __restrict__ HT) {
  __shared__ u16 As[128 * RSA];
  __shared__ u16 Bs[128 * RSA];
  const int lb = blockIdx.x * 128;
  const int cb = blockIdx.y * 128;
  const int b  = blockIdx.z;
  f32x4 acc0[4][4] = {};
  f32x4 accd[4][4];
  gemm_core3<C_, 1>(Y3T + ((size_t)b * L_ + lb) * C_,
                    W1B + (size_t)cb * C_, W1B + (size_t)(cb + 64) * C_,
                    As, Bs, acc0, accd);
  const int lane = threadIdx.x & 63;
  const int wid = threadIdx.x >> 6;
  const int wl = (wid & 1) * 64;
  const int wc = (wid >> 1) * 64;
  const int frow = lane & 15;
  const int fq = (lane >> 4) * 4;
  #pragma unroll
  for (int fi = 0; fi < 4; ++fi) {
    const int lg = lb + wl + fi * 16 + fq;
    #pragma unroll
    for (int fj = 0; fj < 4; ++fj) {
      const int hg = cb + wc + fj * 16 + frow;
      const float bo = b1[hg];
      u16* d = HT + ((size_t)b * L_ + lg) * C_ + hg;
      #pragma unroll
      for (int i = 0; i < 4; ++i) d[(size_t)i * C_] = f2b(geluf(acc0[fi][fj][i] + bo));
    }
  }
}

// ---------------- final: out = x2 + gate_cm * (w2@H + b2) ----------------
__global__ __launch_bounds__(256) void k_final(const u16* __restrict__ HT,
                                               const u16* __restrict__ W2B,
                                               const float* __restrict__ b2,
                                               const u16* __restrict__ AWB,
                                               const float* __restrict__ ada_b,
                                               const u16* __restrict__ STT,
                                               float* __restrict__ out,
                                               int gbase) {
  __shared__ u16 As[128 * RSA];
  __shared__ u16 Bs[128 * RSA];
  const int lb = blockIdx.x * 128;
  const int cb = blockIdx.y * 128;
  const int b  = blockIdx.z;
  f32x4 accM[4][4] = {};
  f32x4 accG[4][4] = {};
  f32x4 accd[4][4];
  gemm_core3<C_, 1>(HT + ((size_t)b * L_ + lb) * C_,
                    W2B + (size_t)cb * C_, W2B + (size_t)(cb + 64) * C_,
                    As, Bs, accM, accd);
  gemm_core3<KADA, 1>(STT + ((size_t)b * L_ + lb) * KADA,
                      AWB + (size_t)(gbase + cb) * KADA,
                      AWB + (size_t)(gbase + cb + 64) * KADA,
                      As, Bs, accG, accd);
  const int lane = threadIdx.x & 63;
  const int wid = threadIdx.x >> 6;
  const int wl = (wid & 1) * 64;
  const int wc = (wid >> 1) * 64;
  const int frow = lane & 15;
  const int fq = (lane >> 4) * 4;
  #pragma unroll
  for (int fi = 0; fi < 4; ++fi) {
    const int lg = lb + wl + fi * 16 + fq;
    #pragma unroll
    for (int fj = 0; fj < 4; ++fj) {
      const int cg = cb + wc + fj * 16 + frow;
      const float bo = b2[cg];
      const float bg = ada_b[gbase + cg];
      const size_t n = ((size_t)b * C_ + cg) * L_ + lg;
      const float4 xv = ld4(out + n);
      float4 o;
      o.x = xv.x + (accG[fi][fj][0] + bg) * (accM[fi][fj][0] + bo);
      o.y = xv.y + (accG[fi][fj][1] + bg) * (accM[fi][fj][1] + bo);
      o.z = xv.z + (accG[fi][fj][2] + bg) * (accM[fi][fj][2] + bo);
      o.w = xv.w + (accG[fi][fj][3] + bg) * (accM[fi][fj][3] + bo);
      st4(out + n, o);
    }
  }
}

// ---------------- conv W32: 2 waves/row, 32 consecutive outputs/thread ----------------
// Q[i] = P[i-512] (f32), f4 idx q: 0..127 zero-pad, 128..1151 data, 1152..1279 total-pad.
// Outputs l = 32t+4g+e (t<128, g<8, e<4); tap f32 idx = 1024+l-SS-r*REP.
__device__ __forceinline__ int z16(int q) { return q ^ ((q >> 4) & 7); }

__global__ __launch_bounds__(128) void k_convW32(const float* __restrict__ Ymod,
                                                 const float* __restrict__ x,
                                                 const u16* __restrict__ G,
                                                 const float* __restrict__ wb,
                                                 const float* __restrict__ Dv,
                                                 float* __restrict__ out) {
  __shared__ f4 Q4s[1280];
  __shared__ float wsum[2];
  const int t = threadIdx.x;    // 0..127
  const int lane = t & 63;
  const int wid = t >> 6;
  const int c = blockIdx.x % C_;
  const size_t rowoff = (size_t)blockIdx.x * L_;
  const float Dc = Dv[c];

  // ---- phase 1: load 32 y_mod, acc = y*Dc, 2-wave scan, store P ----
  f4 acc[8];
  {
    const float* yrow = Ymod + rowoff + 32 * t;
    f4 y[8];
    #pragma unroll
    for (int j = 0; j < 8; ++j) y[j] = *reinterpret_cast<const f4*>(yrow + 4 * j);
    #pragma unroll
    for (int g = 0; g < 8; ++g) acc[g] = y[g] * Dc;
    float run = 0.f;
    #pragma unroll
    for (int j = 0; j < 8; ++j) {
      y[j][0] += run; y[j][1] += y[j][0]; y[j][2] += y[j][1]; y[j][3] += y[j][2];
      run = y[j][3];
    }
    float incl = run;
    #pragma unroll
    for (int d = 1; d < 64; d <<= 1) {
      const float tv = __shfl_up(incl, d, 64);
      if (lane >= d) incl += tv;
    }
    if (lane == 63) wsum[wid] = incl;
    Q4s[z16(t)] = f4{0.f, 0.f, 0.f, 0.f};   // zero pad f4 0..127
    __syncthreads();
    const float wbase = wid ? wsum[0] : 0.f;
    const float total = wsum[0] + wsum[1];
    const float base = (incl - run) + wbase;
    #pragma unroll
    for (int j = 0; j < 8; ++j) {
      f4 vv = y[j];
      vv[0] += base; vv[1] += base; vv[2] += base; vv[3] += base;
      Q4s[z16(128 + 8 * t + j)] = vv;
    }
    Q4s[z16(1152 + t)] = f4{total, total, total, total};   // total pad f4 1152..1279
  }
  __syncthreads();

  const float* wrow = wb + c * NB;   // wave-uniform -> s_load

  // ---- seg5: SS=512 REP=16. f4 = 128+8t+g-4r; r=32-k -> 8t+g+4k
  {
    f4 W[8];
    #pragma unroll
    for (int g = 0; g < 8; ++g) W[g] = Q4s[z16(8 * t + g)];
    for (int kb = 0; kb < 8; ++kb) {
      #pragma unroll
      for (int u = 0; u < 4; ++u) {
        const int k = 4 * kb + u;
        const float wr = wrow[197 - k];
        #pragma unroll
        for (int g = 0; g < 8; ++g) acc[g] += wr * W[(g + 4 * u) & 7];
        #pragma unroll
        for (int d = 0; d < 4; ++d)
          W[(4 * u + d) & 7] = Q4s[z16(8 * t + 8 + 4 * k + d)];
      }
    }
    const float wr = wrow[165];
    #pragma unroll
    for (int g = 0; g < 8; ++g) acc[g] += wr * W[g];
  }

  // ---- seg4: SS=256 REP=8. f4 = 192+8t+g-2r; r=32-k -> 128+8t+g+2k
  {
    f4 W[8];
    #pragma unroll
    for (int g = 0; g < 8; ++g) W[g] = Q4s[z16(128 + 8 * t + g)];
    for (int kb = 0; kb < 4; ++kb) {
      #pragma unroll
      for (int u = 0; u < 8; ++u) {
        const int k = 8 * kb + u;
        const float wr = wrow[164 - k];
        #pragma unroll
        for (int g = 0; g < 8; ++g) acc[g] += wr * W[(g + 2 * u) & 7];
        #pragma unroll
        for (int d = 0; d < 2; ++d)
          W[(2 * u + d) & 7] = Q4s[z16(128 + 8 * t + 8 + 2 * k + d)];
      }
    }
    const float wr = wrow[132];
    #pragma unroll
    for (int g = 0; g < 8; ++g) acc[g] += wr * W[g];
  }

  // ---- seg3: SS=128 REP=4. f4 = 224+8t+g-r; r=32-k -> 192+8t+g+k
  {
    f4 W[8];
    #pragma unroll
    for (int g = 0; g < 8; ++g) W[g] = Q4s[z16(192 + 8 * t + g)];
    for (int kb = 0; kb < 4; ++kb) {
      #pragma unroll
      for (int u = 0; u < 8; ++u) {
        const int k = 8 * kb + u;
        const float wr = wrow[131 - k];
        #pragma unroll
        for (int g = 0; g < 8; ++g) acc[g] += wr * W[(g + u) & 7];
        W[u & 7] = Q4s[z16(192 + 8 * t + 8 + k)];
      }
    }
    const float wr = wrow[99];
    #pragma unroll
    for (int g = 0; g < 8; ++g) acc[g] += wr * W[g];
  }

  // ---- seg2: SS=64 REP=2. even r=2h: f4 240+8t+g-h; odd r=2h+1 straddles.
  {
    f4 W[9];
    #pragma unroll
    for (int j = 0; j < 9; ++j) W[j] = Q4s[z16(223 + 8 * t + j)];
    {
      const float we = wrow[66 + 32];          // h=16, even only
      #pragma unroll
      for (int g = 0; g < 8; ++g) acc[g] += we * W[1 + g];
    }
    for (int h = 15; h >= 0; --h) {
      #pragma unroll
      for (int j = 0; j < 8; ++j) W[j] = W[j + 1];
      W[8] = Q4s[z16(247 + 8 * t - h)];
      const float we = wrow[66 + 2 * h];
      const float wo = wrow[66 + 2 * h + 1];
      #pragma unroll
      for (int g = 0; g < 8; ++g) {
        acc[g] += we * W[1 + g];
        acc[g][0] += wo * W[g][2];
        acc[g][1] += wo * W[g][3];
        acc[g][2] += wo * W[1 + g][0];
        acc[g][3] += wo * W[1 + g][1];
      }
    }
  }

  // ---- seg1: SS=32 REP=1. f4 = 248+8t+g-s (r=4s+u), straddle on u.
  {
    f4 W[9];
    #pragma unroll
    for (int j = 0; j < 9; ++j) W[j] = Q4s[z16(239 + 8 * t + j)];
    {
      const float w0 = wrow[33 + 32];          // s=8, u=0 only
      #pragma unroll
      for (int g = 0; g < 8; ++g) acc[g] += w0 * W[1 + g];
    }
    for (int s = 7; s >= 0; --s) {
      #pragma unroll
      for (int j = 0; j < 8; ++j) W[j] = W[j + 1];
      W[8] = Q4s[z16(255 + 8 * t - s)];
      #pragma unroll
      for (int u = 0; u < 4; ++u) {
        const float wr = wrow[33 + 4 * s + u];
        #pragma unroll
        for (int g = 0; g < 8; ++g) {
          #pragma unroll
          for (int e = 0; e < 4; ++e) {
            const float pv = (e >= u) ? W[1 + g][e - u] : W[g][4 + e - u];
            acc[g][e] += wr * pv;
          }
        }
      }
    }
  }

  // ---- seg0: SS=0 REP=1. f4 = 256+8t+g-s.
  {
    f4 W[9];
    #pragma unroll
    for (int j = 0; j < 9; ++j) W[j] = Q4s[z16(247 + 8 * t + j)];
    {
      const float w0 = wrow[32];               // s=8, u=0 only
      #pragma unroll
      for (int g = 0; g < 8; ++g) acc[g] += w0 * W[1 + g];
    }
    for (int s = 7; s >= 0; --s) {
      #pragma unroll
      for (int j = 0; j < 8; ++j) W[j] = W[j + 1];
      W[8] = Q4s[z16(263 + 8 * t - s)];
      #pragma unroll
      for (int u = 0; u < 4; ++u) {
        const float wr = wrow[4 * s + u];
        #pragma unroll
        for (int g = 0; g < 8; ++g) {
          #pragma unroll
          for (int e = 0; e < 4; ++e) {
            const float pv = (e >= u) ? W[1 + g][e - u] : W[g][4 + e - u];
            acc[g][e] += wr * pv;
          }
        }
      }
    }
  }

  // ---- phase 3: out = x + G * acc ----
  const float* xrow = x + rowoff + 32 * t;
  const u16*  grow = G + rowoff + 32 * t;
  float* orow = out + rowoff + 32 * t;
  #pragma unroll
  for (int a = 0; a < 4; ++a) {
    const bf16x8 gv = ldb8(grow + 8 * a);
    #pragma unroll
    for (int half = 0; half < 2; ++half) {
      const int g = 2 * a + half;
      const f4 xv = *reinterpret_cast<const f4*>(xrow + 8 * a + 4 * half);
      f4 o;
      #pragma unroll
      for (int e = 0; e < 4; ++e)
        o[e] = xv[e] + b2f((u16)gv[4 * half + e]) * acc[g][e];
      *reinterpret_cast<f4*>(orow + 8 * a + 4 * half) = o;
    }
  }
}

}  // namespace

extern "C" void kernel_launch(void* const* d_in, const int* in_sizes, int n_in,
                              void* d_out, int out_size, void* d_ws, size_t ws_size,
                              hipStream_t stream) {
  const float* x      = (const float*)d_in[0];
  const float* t_cond = (const float*)d_in[1];
  const float* kern   = (const float*)d_in[2];
  const float* Dv     = (const float*)d_in[3];
  const float* ada_w  = (const float*)d_in[4];
  const float* ada_b  = (const float*)d_in[5];
  const float* w1     = (const float*)d_in[6];
  const float* b1     = (const float*)d_in[7];
  const float* w2     = (const float*)d_in[8];
  const float* b2     = (const float*)d_in[9];
  float* out = (float*)d_out;

  float* wsf = (float*)d_ws;
  float* A    = wsf;                                     // B*C*L f32 (y_mod)
  float* MV   = A + (size_t)B_ * C_ * L_;
  float* WB   = MV + 4 * (size_t)B_ * L_;
  u16* AWB = (u16*)(WB + (size_t)C_ * NB);
  u16* W1B = AWB + (size_t)6 * C_ * KADA;
  u16* W2B = W1B + (size_t)C_ * C_;
  u16* STT = W2B + (size_t)C_ * C_;
  u16* Y3T = STT + (size_t)B_ * L_ * KADA;               // aliased: G first, Y3T later
  u16* HT  = Y3T + (size_t)B_ * L_ * C_;
  u16* G   = Y3T;                                        // G consumed before Y3T written
  float* mu1 = MV;
  float* rs1 = MV + (size_t)B_ * L_;
  float* mu2 = MV + 2 * (size_t)B_ * L_;
  float* rs2 = MV + 3 * (size_t)B_ * L_;

  (void)in_sizes; (void)n_in; (void)out_size; (void)ws_size;

  const dim3 gg2(L_ / 128, 6, B_);   // dual-output ada GEMMs (64c of each mat)
  const dim3 gg3(L_ / 128, 3, B_);   // 128c single-output GEMMs

  k_kw<<<C_, 64, 0, stream>>>(kern, WB);
  k_wcvt<<<(6 * C_ * KADA) / 2048, 256, 0, stream>>>(ada_w, AWB);
  k_wcvt<<<(C_ * C_) / 2048, 256, 0, stream>>>(w1, W1B);
  k_wcvt<<<(C_ * C_) / 2048, 256, 0, stream>>>(w2, W2B);
  k_tsilu<<<dim3(L_ / 64, KADA / 64, B_), 256, 0, stream>>>(t_cond, STT);

  k_mv4<<<(B_ * L_ / 4) / 256, 256, 0, stream>>>(x, mu1, rs1);
  // LN1 modulate -> y_mod (A)
  k_adagemm<0><<<gg2, 256, 0, stream>>>(AWB, ada_b, STT, x, mu1, rs1, A, nullptr, 0, C_);
  // gate_tm -> G (bf16 [c][l])
  k_adagemm<2><<<gg3, 256, 0, stream>>>(AWB, ada_b, STT, nullptr, nullptr, nullptr, nullptr, G, 2 * C_, 0);
  // fused 2-wave scan + conv + gated residual -> out = x2
  k_convW32<<<B_ * C_, 128, 0, stream>>>(A, x, G, WB, Dv, out);
  // LN2 stats + modulate -> Y3T (bf16 transposed)
  k_mv4<<<(B_ * L_ / 4) / 256, 256, 0, stream>>>(out, mu2, rs2);
  k_adagemm<1><<<gg2, 256, 0, stream>>>(AWB, ada_b, STT, out, mu2, rs2, nullptr, Y3T, 3 * C_, 4 * C_);
  // MLP
  k_mlp1<<<gg3, 256, 0, stream>>>(Y3T, W1B, b1, HT);
  k_final<<<gg3, 256, 0, stream>>>(HT, W2B, b2, AWB, ada_b, STT, out, 5 * C_);
}

// Round 12
// 530.866 us; speedup vs baseline: 1.8247x; 1.8247x over previous
//
#include <hip/hip_runtime.h>
#include <cstddef>
#include <cstdint>

// AdaConvBlock on MI355X — round 12: exact revert to round 7 (best: 532us).
// Scan offsets precomputed (mode0 epilogue -> Part, k_off -> exclusive chunk
// offsets), k_convG rebuilds the prefix row with a barrier-free shfl scan,
// runs the r4 conv body (124-VGPR profile), applies out = x + G*y2.

namespace {

constexpr int B_  = 16;
constexpr int C_  = 384;
constexpr int L_  = 4096;
constexpr int KADA = 128;
constexpr int KS  = 32;
constexpr int NB  = 6 * 33;
constexpr float EPS_ = 1e-5f;
constexpr int RSA = 136;        // LDS row stride (bf16) for staged tiles

typedef unsigned short u16;
typedef __attribute__((ext_vector_type(8))) short bf16x8;
typedef __attribute__((ext_vector_type(4))) float f32x4;
typedef __attribute__((ext_vector_type(4))) float f4;

__device__ __forceinline__ float4 ld4(const float* p) { return *reinterpret_cast<const float4*>(p); }
__device__ __forceinline__ void st4(float* p, float4 v) { *reinterpret_cast<float4*>(p) = v; }
__device__ __forceinline__ float siluf(float z) { return z / (1.f + expf(-z)); }
__device__ __forceinline__ float geluf(float z) { return 0.5f * z * (1.f + erff(z * 0.70710678118654752f)); }
__device__ __forceinline__ u16 f2b(float x) {
  union { float f; uint32_t u; } a; a.f = x;
  const uint32_t u = a.u;
  return (u16)((u + 0x7fffu + ((u >> 16) & 1u)) >> 16);
}
__device__ __forceinline__ float b2f(u16 h) {
  union { uint32_t u; float f; } a; a.u = ((uint32_t)h) << 16; return a.f;
}
__device__ __forceinline__ bf16x8 ldb8(const u16* p) { return *reinterpret_cast<const bf16x8*>(p); }
__device__ __forceinline__ void stb8(u16* p, bf16x8 v) { *reinterpret_cast<bf16x8*>(p) = v; }

// ---------------- boundary-weight precompute (per channel) ----------------
__global__ __launch_bounds__(64) void k_kw(const float* __restrict__ kern, float* __restrict__ wb) {
  const int c = blockIdx.x;
  const int t = threadIdx.x;
  constexpr float SC[6] = {32.f, 16.f, 8.f, 4.f, 2.f, 1.f};
  constexpr int REP[6] = {1, 1, 2, 4, 8, 16};
  float part = 0.f;
  for (int idx = t; idx < 192; idx += 64) {
    const int i = idx >> 5, r = idx & 31;
    const float v = kern[(i * C_ + c) * KS + r] * SC[i];
    part += v * v * (float)REP[i];
  }
  for (int m = 1; m < 64; m <<= 1) part += __shfl_xor(part, m);
  const float rinv = 1.f / sqrtf(part);
  for (int jj = t; jj < NB; jj += 64) {
    const int i = jj / 33, r = jj - 33 * i;
    const float sc = SC[i] * rinv;
    float bwv;
    if (r == 0) bwv = kern[(i * C_ + c) * KS + 0] * sc;
    else if (r == 32) bwv = -kern[(i * C_ + c) * KS + 31] * sc;
    else bwv = (kern[(i * C_ + c) * KS + r] - kern[(i * C_ + c) * KS + r - 1]) * sc;
    wb[c * NB + jj] = bwv;
  }
}

// ---------------- weight f32 -> bf16 convert ----------------
__global__ __launch_bounds__(256) void k_wcvt(const float* __restrict__ src, u16* __restrict__ dst) {
  const size_t i = ((size_t)blockIdx.x * 256 + threadIdx.x) * 8;
  const float4 a = ld4(src + i);
  const float4 b = ld4(src + i + 4);
  bf16x8 v;
  v[0] = (short)f2b(a.x); v[1] = (short)f2b(a.y); v[2] = (short)f2b(a.z); v[3] = (short)f2b(a.w);
  v[4] = (short)f2b(b.x); v[5] = (short)f2b(b.y); v[6] = (short)f2b(b.z); v[7] = (short)f2b(b.w);
  stb8(dst + i, v);
}

// ---------------- STT[b][l][128] = bf16(silu(t_cond[b][k][l])) ----------------
__global__ __launch_bounds__(256) void k_tsilu(const float* __restrict__ in, u16* __restrict__ out) {
  __shared__ float T[64][65];
  const int t = threadIdx.x;
  const int lb = blockIdx.x * 64;
  const int kb = blockIdx.y * 64;
  const int b  = blockIdx.z;
  const float* src = in + ((size_t)b * KADA + kb) * L_ + lb;
  const int ll = t & 63;
  const int kq = t >> 6;
  #pragma unroll
  for (int j = 0; j < 16; ++j) {
    const int k = kq * 16 + j;
    T[k][ll] = siluf(src[(size_t)k * L_ + ll]);
  }
  __syncthreads();
  const int g = t & 7;
  #pragma unroll
  for (int j = 0; j < 2; ++j) {
    const int l = (t >> 3) + 32 * j;
    bf16x8 v;
    #pragma unroll
    for (int i = 0; i < 8; ++i) v[i] = (short)f2b(T[8 * g + i][l]);
    stb8(out + ((size_t)b * L_ + lb + l) * KADA + kb + 8 * g, v);
  }
}

// ---------------- per-(b,l) mean / rsigma over C, 4 l per thread ----------------
__global__ __launch_bounds__(256) void k_mv4(const float* __restrict__ x,
                                             float* __restrict__ mu, float* __restrict__ rs) {
  const int g4 = blockIdx.x * 256 + threadIdx.x;   // [0, B*L/4)
  const int b = g4 >> 10;
  const int l = (g4 & 1023) * 4;
  const float* p = x + (size_t)b * C_ * L_ + l;
  f4 s = {0.f, 0.f, 0.f, 0.f}, ss = {0.f, 0.f, 0.f, 0.f};
  #pragma unroll 4
  for (int c = 0; c < C_; ++c) {
    const f4 v = *reinterpret_cast<const f4*>(p + (size_t)c * L_);
    s += v; ss += v * v;
  }
  f4 m4, r4;
  #pragma unroll
  for (int e = 0; e < 4; ++e) {
    const float m = s[e] * (1.f / (float)C_);
    const float var = ss[e] * (1.f / (float)C_) - m * m;
    m4[e] = m;
    r4[e] = 1.f / sqrtf(var + EPS_);
  }
  *reinterpret_cast<f4*>(mu + (size_t)b * L_ + l) = m4;
  *reinterpret_cast<f4*>(rs + (size_t)b * L_ + l) = r4;
}

// ---------------- MFMA GEMM core v3 ----------------
template <int KD, int NBOP>
__device__ __forceinline__ void gemm_core3(const u16* __restrict__ Ab,
                                           const u16* __restrict__ B0b,
                                           const u16* __restrict__ B1b,
                                           u16* As, u16* Bs,
                                           f32x4 (&acc0)[4][4], f32x4 (&acc1)[4][4]) {
  constexpr int WC = (NBOP == 2) ? 2 : 4;
  const int tid = threadIdx.x;
  const int lane = tid & 63;
  const int wid = tid >> 6;
  const int wl = (wid & 1) * 64;
  const int wc = (wid >> 1) * ((NBOP == 2) ? 32 : 64);
  const int frow = lane & 15;
  const int fk8 = (lane >> 4) * 8;
  const int rr = tid >> 4;            // staging row 0..15
  const int c8 = (tid & 15) * 8;      // staging col

  for (int kc = 0; kc < KD; kc += 128) {
    __syncthreads();
    #pragma unroll
    for (int j = 0; j < 8; ++j)
      stb8(As + (j * 16 + rr) * RSA + c8, ldb8(Ab + (size_t)(j * 16 + rr) * KD + kc + c8));
    #pragma unroll
    for (int j = 0; j < 4; ++j)
      stb8(Bs + (j * 16 + rr) * RSA + c8, ldb8(B0b + (size_t)(j * 16 + rr) * KD + kc + c8));
    #pragma unroll
    for (int j = 0; j < 4; ++j)
      stb8(Bs + ((j + 4) * 16 + rr) * RSA + c8, ldb8(B1b + (size_t)(j * 16 + rr) * KD + kc + c8));
    __syncthreads();
    #pragma unroll
    for (int ks = 0; ks < 128; ks += 32) {
      bf16x8 af[4], b0f[WC], b1f[WC];
      #pragma unroll
      for (int fi = 0; fi < 4; ++fi)
        af[fi] = ldb8(As + (wl + fi * 16 + frow) * RSA + ks + fk8);
      #pragma unroll
      for (int fj = 0; fj < WC; ++fj) {
        b0f[fj] = ldb8(Bs + (wc + fj * 16 + frow) * RSA + ks + fk8);
        if constexpr (NBOP == 2)
          b1f[fj] = ldb8(Bs + (64 + wc + fj * 16 + frow) * RSA + ks + fk8);
      }
      #pragma unroll
      for (int fi = 0; fi < 4; ++fi)
        #pragma unroll
        for (int fj = 0; fj < WC; ++fj) {
          acc0[fi][fj] = __builtin_amdgcn_mfma_f32_16x16x32_bf16(af[fi], b0f[fj], acc0[fi][fj], 0, 0, 0);
          if constexpr (NBOP == 2)
            acc1[fi][fj] = __builtin_amdgcn_mfma_f32_16x16x32_bf16(af[fi], b1f[fj], acc1[fi][fj], 0, 0, 0);
        }
    }
  }
}

// ---------------- ada GEMMs ----------------
// MODE 0: LN1-mod -> y_mod f32 [c][l] + Part chunk sums (block 128l x 64c, dual)
// MODE 1: LN2-mod -> Y3T bf16 [l][c]  (block 128l x 64c, dual)
// MODE 2: gate_tm -> G bf16 [c][l]    (block 128l x 128c)
template <int MODE>
__global__ __launch_bounds__(256) void k_adagemm(const u16* __restrict__ AWB,
                                                 const float* __restrict__ ada_b,
                                                 const u16* __restrict__ STT,
                                                 const float* __restrict__ src,
                                                 const float* __restrict__ mu,
                                                 const float* __restrict__ rs,
                                                 float* __restrict__ dstf,
                                                 u16* __restrict__ dstb,
                                                 float* __restrict__ part,
                                                 int base0, int base1) {
  __shared__ u16 As[128 * RSA];
  __shared__ u16 Bs[128 * RSA];
  const int lb = blockIdx.x * 128;
  const int b  = blockIdx.z;
  f32x4 acc0[4][4] = {};
  f32x4 acc1[4][4] = {};
  constexpr int NBOP = (MODE == 2) ? 1 : 2;
  const int cb = blockIdx.y * ((MODE == 2) ? 128 : 64);
  const u16* B0b;
  const u16* B1b;
  if constexpr (MODE == 2) {
    B0b = AWB + (size_t)(base0 + cb) * KADA;
    B1b = AWB + (size_t)(base0 + cb + 64) * KADA;
  } else {
    B0b = AWB + (size_t)(base0 + cb) * KADA;
    B1b = AWB + (size_t)(base1 + cb) * KADA;
  }
  gemm_core3<KADA, NBOP>(STT + ((size_t)b * L_ + lb) * KADA, B0b, B1b, As, Bs, acc0, acc1);

  const int lane = threadIdx.x & 63;
  const int wid = threadIdx.x >> 6;
  const int wl = (wid & 1) * 64;
  const int wc = (wid >> 1) * ((NBOP == 2) ? 32 : 64);
  const int frow = lane & 15;
  const int fq = (lane >> 4) * 4;
  constexpr int WC = (NBOP == 2) ? 2 : 4;
  float csum[2] = {0.f, 0.f};
  #pragma unroll
  for (int fi = 0; fi < 4; ++fi) {
    const int lg = lb + wl + fi * 16 + fq;
    float4 m4, r4;
    if (MODE != 2) { m4 = ld4(mu + (size_t)b * L_ + lg); r4 = ld4(rs + (size_t)b * L_ + lg); }
    #pragma unroll
    for (int fj = 0; fj < WC; ++fj) {
      const int cg = cb + wc + fj * 16 + frow;
      const size_t n = ((size_t)b * C_ + cg) * L_ + lg;
      if (MODE == 2) {
        const float bg = ada_b[base0 + cg];
        const u16 h0 = f2b(acc0[fi][fj][0] + bg);
        const u16 h1 = f2b(acc0[fi][fj][1] + bg);
        const u16 h2 = f2b(acc0[fi][fj][2] + bg);
        const u16 h3 = f2b(acc0[fi][fj][3] + bg);
        uint2 pk;
        pk.x = (uint32_t)h0 | ((uint32_t)h1 << 16);
        pk.y = (uint32_t)h2 | ((uint32_t)h3 << 16);
        *reinterpret_cast<uint2*>(dstb + n) = pk;
      } else {
        const float bsh = ada_b[base0 + cg];
        const float bsc = ada_b[base1 + cg];
        const float4 xv = ld4(src + n);
        float o[4];
        o[0] = (xv.x - m4.x) * r4.x * (1.f + acc1[fi][fj][0] + bsc) + acc0[fi][fj][0] + bsh;
        o[1] = (xv.y - m4.y) * r4.y * (1.f + acc1[fi][fj][1] + bsc) + acc0[fi][fj][1] + bsh;
        o[2] = (xv.z - m4.z) * r4.z * (1.f + acc1[fi][fj][2] + bsc) + acc0[fi][fj][2] + bsh;
        o[3] = (xv.w - m4.w) * r4.w * (1.f + acc1[fi][fj][3] + bsc) + acc0[fi][fj][3] + bsh;
        if (MODE == 0) {
          st4(dstf + n, float4{o[0], o[1], o[2], o[3]});
          csum[fj] += (o[0] + o[1]) + (o[2] + o[3]);
        } else {
          u16* d = dstb + ((size_t)b * L_ + lg) * C_ + cg;
          #pragma unroll
          for (int i = 0; i < 4; ++i) d[(size_t)i * C_] = f2b(o[i]);
        }
      }
    }
  }
  // MODE 0: reduce per-(c, 128-l-chunk) sums -> Part[b][c][chunk]
  if constexpr (MODE == 0) {
    __syncthreads();                 // all waves done with As/Bs
    float* S = reinterpret_cast<float*>(As);   // [2 l-halves][64 channels]
    #pragma unroll
    for (int fj = 0; fj < 2; ++fj) {
      float v = csum[fj];
      v += __shfl_xor(v, 16);
      v += __shfl_xor(v, 32);
      if (lane < 16) S[(wid & 1) * 64 + wc + fj * 16 + frow] = v;
    }
    __syncthreads();
    if (threadIdx.x < 64) {
      const int cg = cb + threadIdx.x;
      part[((size_t)b * C_ + cg) * 32 + blockIdx.x] = S[threadIdx.x] + S[64 + threadIdx.x];
    }
  }
}

// ---------------- k_off: Part[row][32] -> exclusive offsets + total ----------------
__global__ __launch_bounds__(256) void k_off(const float* __restrict__ part,
                                             float* __restrict__ off) {
  const int tid = threadIdx.x;
  const int row = blockIdx.x * 8 + (tid >> 5);
  const int j = tid & 31;
  const float v = part[(size_t)row * 32 + j];
  float incl = v;
  #pragma unroll
  for (int d = 1; d < 32; d <<= 1) {
    const float t = __shfl_up(incl, d, 32);
    if (j >= d) incl += t;
  }
  off[(size_t)row * 33 + j] = incl - v;
  if (j == 31) off[(size_t)row * 33 + 32] = incl;
}

// ---------------- MLP GEMM1: HT[l][h] = bf16(gelu(w1 @ y3 + b1)) ----------------
__global__ __launch_bounds__(256) void k_mlp1(const u16* __restrict__ Y3T,
                                              const u16* __restrict__ W1B,
                                              const float* __restrict__ b1,
                                              u16* __restrict__ HT) {
  __shared__ u16 As[128 * RSA];
  __shared__ u16 Bs[128 * RSA];
  const int lb = blockIdx.x * 128;
  const int cb = blockIdx.y * 128;
  const int b  = blockIdx.z;
  f32x4 acc0[4][4] = {};
  f32x4 accd[4][4];
  gemm_core3<C_, 1>(Y3T + ((size_t)b * L_ + lb) * C_,
                    W1B + (size_t)cb * C_, W1B + (size_t)(cb + 64) * C_,
                    As, Bs, acc0, accd);
  const int lane = threadIdx.x & 63;
  const int wid = threadIdx.x >> 6;
  const int wl = (wid & 1) * 64;
  const int wc = (wid >> 1) * 64;
  const int frow = lane & 15;
  const int fq = (lane >> 4) * 4;
  #pragma unroll
  for (int fi = 0; fi < 4; ++fi) {
    const int lg = lb + wl + fi * 16 + fq;
    #pragma unroll
    for (int fj = 0; fj < 4; ++fj) {
      const int hg = cb + wc + fj * 16 + frow;
      const float bo = b1[hg];
      u16* d = HT + ((size_t)b * L_ + lg) * C_ + hg;
      #pragma unroll
      for (int i = 0; i < 4; ++i) d[(size_t)i * C_] = f2b(geluf(acc0[fi][fj][i] + bo));
    }
  }
}

// ---------------- final: out = x2 + gate_cm * (w2@H + b2) ----------------
__global__ __launch_bounds__(256) void k_final(const u16* __restrict__ HT,
                                               const u16* __restrict__ W2B,
                                               const float* __restrict__ b2,
                                               const u16* __restrict__ AWB,
                                               const float* __restrict__ ada_b,
                                               const u16* __restrict__ STT,
                                               float* __restrict__ out,
                                               int gbase) {
  __shared__ u16 As[128 * RSA];
  __shared__ u16 Bs[128 * RSA];
  const int lb = blockIdx.x * 128;
  const int cb = blockIdx.y * 128;
  const int b  = blockIdx.z;
  f32x4 accM[4][4] = {};
  f32x4 accG[4][4] = {};
  f32x4 accd[4][4];
  gemm_core3<C_, 1>(HT + ((size_t)b * L_ + lb) * C_,
                    W2B + (size_t)cb * C_, W2B + (size_t)(cb + 64) * C_,
                    As, Bs, accM, accd);
  gemm_core3<KADA, 1>(STT + ((size_t)b * L_ + lb) * KADA,
                      AWB + (size_t)(gbase + cb) * KADA,
                      AWB + (size_t)(gbase + cb + 64) * KADA,
                      As, Bs, accG, accd);
  const int lane = threadIdx.x & 63;
  const int wid = threadIdx.x >> 6;
  const int wl = (wid & 1) * 64;
  const int wc = (wid >> 1) * 64;
  const int frow = lane & 15;
  const int fq = (lane >> 4) * 4;
  #pragma unroll
  for (int fi = 0; fi < 4; ++fi) {
    const int lg = lb + wl + fi * 16 + fq;
    #pragma unroll
    for (int fj = 0; fj < 4; ++fj) {
      const int cg = cb + wc + fj * 16 + frow;
      const float bo = b2[cg];
      const float bg = ada_b[gbase + cg];
      const size_t n = ((size_t)b * C_ + cg) * L_ + lg;
      const float4 xv = ld4(out + n);
      float4 o;
      o.x = xv.x + (accG[fi][fj][0] + bg) * (accM[fi][fj][0] + bo);
      o.y = xv.y + (accG[fi][fj][1] + bg) * (accM[fi][fj][1] + bo);
      o.z = xv.z + (accG[fi][fj][2] + bg) * (accM[fi][fj][2] + bo);
      o.w = xv.w + (accG[fi][fj][3] + bg) * (accM[fi][fj][3] + bo);
      st4(out + n, o);
    }
  }
}

// ---------------- conv: register scan + r4 conv body + gated epilogue ----------------
__device__ __forceinline__ int swz(int q) { return q ^ ((q >> 3) & 7); }

__device__ __forceinline__ float wf5(const f4& W0, const f4& W1, const f4& W2,
                                     const f4& W3, const f4& W4, int j) {
  return j < 4 ? W0[j & 3] : j < 8 ? W1[j & 3] : j < 12 ? W2[j & 3]
       : j < 16 ? W3[j & 3] : W4[j & 3];
}
__device__ __forceinline__ float wf4(const f4& W0, const f4& W1, const f4& W2,
                                     const f4& W3, int j) {
  return j < 4 ? W0[j & 3] : j < 8 ? W1[j & 3] : j < 12 ? W2[j & 3] : W3[j & 3];
}

__global__ __launch_bounds__(256) void k_convG(const float* __restrict__ Ymod,
                                               const float* __restrict__ x,
                                               const u16* __restrict__ G,
                                               const float* __restrict__ Off,
                                               const float* __restrict__ wb,
                                               const float* __restrict__ Dv,
                                               float* __restrict__ out) {
  __shared__ f4 Q4s[1280];      // swizzled: Q[i]=P[i-512]; pads 0 / total
  const int tid = threadIdx.x;
  const int c = blockIdx.x % C_;
  const size_t rowoff = (size_t)blockIdx.x * L_;
  const float* offrow = Off + (size_t)blockIdx.x * 33;

  // ---- phase 1: load y_mod, barrier-free scan via chunk offsets ----
  {
    const float* yrow = Ymod + rowoff + 16 * tid;
    f4 v[4];
    #pragma unroll
    for (int j = 0; j < 4; ++j) v[j] = *reinterpret_cast<const f4*>(yrow + 4 * j);
    float run = 0.f;
    #pragma unroll
    for (int j = 0; j < 4; ++j) {
      v[j][0] += run; v[j][1] += v[j][0]; v[j][2] += v[j][1]; v[j][3] += v[j][2];
      run = v[j][3];
    }
    float incl = run;
    #pragma unroll
    for (int d = 1; d < 8; d <<= 1) {
      const float t = __shfl_up(incl, d, 8);
      if ((tid & 7) >= d) incl += t;
    }
    const float base = offrow[tid >> 3] + (incl - run);
    #pragma unroll
    for (int j = 0; j < 4; ++j) {
      v[j][0] += base; v[j][1] += base; v[j][2] += base; v[j][3] += base;
      Q4s[swz(128 + 4 * tid + j)] = v[j];
    }
    const float total = offrow[32];
    if (tid < 128) {
      Q4s[swz(tid)] = f4{0.f, 0.f, 0.f, 0.f};
      Q4s[swz(1152 + tid)] = f4{total, total, total, total};
    }
  }
  __syncthreads();

  // ---- phase 2: conv (r4 body) ----
  const float* wrow = wb + c * NB;    // wave-uniform -> s_load path
  const int qb = 256 + 4 * tid;
  float acc[16];
  #pragma unroll
  for (int i = 0; i < 16; ++i) acc[i] = 0.f;

  // seg0 / seg1: REP=1
  #pragma unroll
  for (int s = 0; s < 2; ++s) {
    const int wbase = s * 33;
    const int q0 = qb - 1 - 8 * s;
    float w[33];
    #pragma unroll
    for (int r = 0; r < 33; ++r) w[r] = wrow[wbase + r];
    f4 W0 = Q4s[swz(q0)],     W1 = Q4s[swz(q0 + 1)], W2 = Q4s[swz(q0 + 2)],
       W3 = Q4s[swz(q0 + 3)], W4 = Q4s[swz(q0 + 4)];
    #pragma unroll
    for (int g = 0; g < 9; ++g) {
      #pragma unroll
      for (int d = 0; d < 4; ++d) {
        if (g < 8 || d == 0) {
          #pragma unroll
          for (int i = 0; i < 16; ++i)
            acc[i] += w[4 * g + d] * wf5(W0, W1, W2, W3, W4, i + 4 - d);
        }
      }
      if (g < 8) { W4 = W3; W3 = W2; W2 = W1; W1 = W0; W0 = Q4s[swz(q0 - 1 - g)]; }
    }
  }
  // seg2: REP=2
  {
    const int q0 = qb - 17;
    float w[33];
    #pragma unroll
    for (int r = 0; r < 33; ++r) w[r] = wrow[66 + r];
    f4 W0 = Q4s[swz(q0)],     W1 = Q4s[swz(q0 + 1)], W2 = Q4s[swz(q0 + 2)],
       W3 = Q4s[swz(q0 + 3)], W4 = Q4s[swz(q0 + 4)];
    #pragma unroll
    for (int h = 0; h < 17; ++h) {
      #pragma unroll
      for (int i = 0; i < 16; ++i)
        acc[i] += w[2 * h] * wf5(W0, W1, W2, W3, W4, i + 4);
      if (h < 16) {
        #pragma unroll
        for (int i = 0; i < 16; ++i)
          acc[i] += w[2 * h + 1] * wf5(W0, W1, W2, W3, W4, i + 2);
        W4 = W3; W3 = W2; W2 = W1; W1 = W0; W0 = Q4s[swz(q0 - 1 - h)];
      }
    }
  }
  // seg3: REP=4
  {
    const int low0 = qb - 32;
    float w[33];
    #pragma unroll
    for (int r = 0; r < 33; ++r) w[r] = wrow[99 + r];
    f4 W0 = Q4s[swz(low0)],     W1 = Q4s[swz(low0 + 1)],
       W2 = Q4s[swz(low0 + 2)], W3 = Q4s[swz(low0 + 3)];
    #pragma unroll
    for (int r = 0; r < 33; ++r) {
      #pragma unroll
      for (int i = 0; i < 16; ++i) acc[i] += w[r] * wf4(W0, W1, W2, W3, i);
      if (r < 32) { W3 = W2; W2 = W1; W1 = W0; W0 = Q4s[swz(low0 - 1 - r)]; }
    }
  }
  // seg4: REP=8
  {
    const int low0 = qb - 64;
    float w[33];
    #pragma unroll
    for (int r = 0; r < 33; ++r) w[r] = wrow[132 + r];
    f4 W0 = Q4s[swz(low0)],     W1 = Q4s[swz(low0 + 1)],
       W2 = Q4s[swz(low0 + 2)], W3 = Q4s[swz(low0 + 3)];
    #pragma unroll
    for (int r = 0; r < 33; ++r) {
      #pragma unroll
      for (int i = 0; i < 16; ++i) acc[i] += w[r] * wf4(W0, W1, W2, W3, i);
      if (r < 32) {
        W3 = W1; W2 = W0;
        W0 = Q4s[swz(low0 - 2 * r - 2)];
        W1 = Q4s[swz(low0 - 2 * r - 1)];
      }
    }
  }
  // seg5: REP=16
  {
    float w[33];
    #pragma unroll
    for (int r = 0; r < 33; ++r) w[r] = wrow[165 + r];
    #pragma unroll
    for (int r = 0; r < 33; ++r) {
      const int lo = qb - 128 - 4 * r;
      const f4 W0 = Q4s[swz(lo)],     W1 = Q4s[swz(lo + 1)],
               W2 = Q4s[swz(lo + 2)], W3 = Q4s[swz(lo + 3)];
      #pragma unroll
      for (int i = 0; i < 16; ++i) acc[i] += w[r] * wf4(W0, W1, W2, W3, i);
    }
  }

  // ---- phase 3: epilogue out = x + g * (conv + ymod*Dc) ----
  const float Dc = Dv[c];
  const int qe = 128 + 4 * tid;
  const f4 E0 = Q4s[swz(qe - 1)], E1 = Q4s[swz(qe)],     E2 = Q4s[swz(qe + 1)],
           E3 = Q4s[swz(qe + 2)], E4 = Q4s[swz(qe + 3)];
  float pm[17];
  #pragma unroll
  for (int j = 0; j < 17; ++j) pm[j] = wf5(E0, E1, E2, E3, E4, j + 3);
  const float* xrow = x + rowoff + 16 * tid;
  const u16* grow = G + rowoff + 16 * tid;
  float* orow = out + rowoff + 16 * tid;
  const bf16x8 g0 = ldb8(grow);
  const bf16x8 g1 = ldb8(grow + 8);
  #pragma unroll
  for (int a = 0; a < 4; ++a) {
    const f4 xv = *reinterpret_cast<const f4*>(xrow + 4 * a);
    f4 o;
    #pragma unroll
    for (int e = 0; e < 4; ++e) {
      const int i = 4 * a + e;
      const float y2 = acc[i] + (pm[i + 1] - pm[i]) * Dc;
      const float gv = b2f((u16)(i < 8 ? g0[i] : g1[i - 8]));
      o[e] = xv[e] + gv * y2;
    }
    *reinterpret_cast<f4*>(orow + 4 * a) = o;
  }
}

}  // namespace

extern "C" void kernel_launch(void* const* d_in, const int* in_sizes, int n_in,
                              void* d_out, int out_size, void* d_ws, size_t ws_size,
                              hipStream_t stream) {
  const float* x      = (const float*)d_in[0];
  const float* t_cond = (const float*)d_in[1];
  const float* kern   = (const float*)d_in[2];
  const float* Dv     = (const float*)d_in[3];
  const float* ada_w  = (const float*)d_in[4];
  const float* ada_b  = (const float*)d_in[5];
  const float* w1     = (const float*)d_in[6];
  const float* b1     = (const float*)d_in[7];
  const float* w2     = (const float*)d_in[8];
  const float* b2     = (const float*)d_in[9];
  float* out = (float*)d_out;

  float* wsf = (float*)d_ws;
  float* A    = wsf;                                     // B*C*L f32 (y_mod)
  float* MV   = A + (size_t)B_ * C_ * L_;
  float* WB   = MV + 4 * (size_t)B_ * L_;
  float* Part = WB + (size_t)C_ * NB;                    // B*C*32 f32
  float* Off  = Part + (size_t)B_ * C_ * 32;             // B*C*33 f32
  u16* AWB = (u16*)(Off + (size_t)B_ * C_ * 33);
  u16* W1B = AWB + (size_t)6 * C_ * KADA;
  u16* W2B = W1B + (size_t)C_ * C_;
  u16* STT = W2B + (size_t)C_ * C_;
  u16* Y3T = STT + (size_t)B_ * L_ * KADA;               // aliased: G first, Y3T later
  u16* HT  = Y3T + (size_t)B_ * L_ * C_;
  u16* G   = Y3T;                                        // G consumed before Y3T written
  float* mu1 = MV;
  float* rs1 = MV + (size_t)B_ * L_;
  float* mu2 = MV + 2 * (size_t)B_ * L_;
  float* rs2 = MV + 3 * (size_t)B_ * L_;

  (void)in_sizes; (void)n_in; (void)out_size; (void)ws_size;

  const dim3 gg2(L_ / 128, 6, B_);   // dual-output ada GEMMs (64c of each mat)
  const dim3 gg3(L_ / 128, 3, B_);   // 128c single-output GEMMs

  k_kw<<<C_, 64, 0, stream>>>(kern, WB);
  k_wcvt<<<(6 * C_ * KADA) / 2048, 256, 0, stream>>>(ada_w, AWB);
  k_wcvt<<<(C_ * C_) / 2048, 256, 0, stream>>>(w1, W1B);
  k_wcvt<<<(C_ * C_) / 2048, 256, 0, stream>>>(w2, W2B);
  k_tsilu<<<dim3(L_ / 64, KADA / 64, B_), 256, 0, stream>>>(t_cond, STT);

  k_mv4<<<(B_ * L_ / 4) / 256, 256, 0, stream>>>(x, mu1, rs1);
  // LN1 modulate -> y_mod (A) + Part chunk sums
  k_adagemm<0><<<gg2, 256, 0, stream>>>(AWB, ada_b, STT, x, mu1, rs1, A, nullptr, Part, 0, C_);
  // chunk offsets
  k_off<<<(B_ * C_) / 8, 256, 0, stream>>>(Part, Off);
  // gate_tm -> G (bf16 [c][l])
  k_adagemm<2><<<gg3, 256, 0, stream>>>(AWB, ada_b, STT, nullptr, nullptr, nullptr, nullptr, G, nullptr, 2 * C_, 0);
  // fused register-scan + conv + gated residual -> out = x2
  k_convG<<<B_ * C_, 256, 0, stream>>>(A, x, G, Off, WB, Dv, out);
  // LN2 stats + modulate -> Y3T (bf16 transposed)
  k_mv4<<<(B_ * L_ / 4) / 256, 256, 0, stream>>>(out, mu2, rs2);
  k_adagemm<1><<<gg2, 256, 0, stream>>>(AWB, ada_b, STT, out, mu2, rs2, nullptr, Y3T, nullptr, 3 * C_, 4 * C_);
  // MLP
  k_mlp1<<<gg3, 256, 0, stream>>>(Y3T, W1B, b1, HT);
  k_final<<<gg3, 256, 0, stream>>>(HT, W2B, b2, AWB, ada_b, STT, out, 5 * C_);
}